// Round 3
// baseline (159.146 us; speedup 1.0000x reference)
//
#include <hip/hip_runtime.h>
#include <cstdint>
#include <cstddef>

// Problem constants (from reference)
#define B_SZ   512
#define DIN    256
#define DOUT   256
#define KNOTS  64
#define NK     63                 // intervals = KNOTS-1
#define HSTEP  (4.0f / 63.0f)
#define INV_H  (63.0f / 4.0f)     // 15.75 exactly; ~1.5e-8 rel diff vs 1/h_f32

// Fused-kernel geometry
#define OS     32                 // outputs per block
#define BT     16                 // samples per block
#define IS     4                  // input dims staged per phase
#define NPH    (DIN / IS)         // 64 phases
#define RSTR   67                 // LDS row stride in floats: 1 left ghost + 64 knots
                                  // + 1 right ghost + 1 pad; odd => banks (3*o+k)%32,
                                  // conflict-free per 32-lane o-group
#define NROW   (IS * OS)          // 128 rows per phase

// ---- PCHIP slope helpers (reference semantics, f32) ----
static __device__ __forceinline__ float pchip_edge(float dA, float dB) {
    // m = (3*dA - dB)/2; zero if m*dA <= 0; clamp to 3*dA on sign flip & too big
    float m = 0.5f * (3.0f * dA - dB);
    if (m * dA <= 0.0f) {
        m = 0.0f;
    } else if (dA * dB < 0.0f && fabsf(m) > 3.0f * fabsf(dA)) {
        m = 3.0f * dA;
    }
    return m;
}

static __device__ __forceinline__ float pchip_inner(float d0, float d1) {
    // harmonic mean if slopes agree in sign, else 0. rcp is 1 ulp; if d0*d1 > 0
    // (not flushed) then |d0+d1| >= 2*sqrt(d0*d1) is far from subnormal -> safe.
    float pr = d0 * d1;
    float hm = 0.0f;
    if (pr > 0.0f) hm = 2.0f * pr * __builtin_amdgcn_rcpf(d0 + d1);
    return hm;
}

// ---- Single fused kernel: no workspace, no table, no atomics ----
// Grid 256 = 32 b-chunks x 8 o-chunks; oc = bid&7 keeps each XCD on one
// 2.1 MB o-slice of y (L2-resident for the 32 blocks sharing it).
// Per phase: register-prefetch next 4 input dims' y rows (coalesced 1 KB/wave),
// stage into ghost-padded LDS, evaluate 4 terms/thread with on-demand slopes.
// Each thread owns exactly one out[b][o]; accumulates across all 256 i.
__global__ __launch_bounds__(512) void kan_fused(const float* __restrict__ x,
                                                 const float* __restrict__ y,
                                                 const float* __restrict__ bias,
                                                 float* __restrict__ out) {
    __shared__ float buf[NROW * RSTR];    // 34,304 B staged y (ghost-padded)
    __shared__ float tT[BT * DIN];        // 16,384 B t-values for (b, i)

    const int bid = blockIdx.x;
    const int oc  = bid & 7;              // XCD-affine o-chunk
    const int bc  = bid >> 3;             // sample chunk
    const int o0  = oc * OS;
    const int b0  = bc * BT;

    const int t   = threadIdx.x;          // 512 threads = 16 b x 32 o
    const int o_l = t & (OS - 1);
    const int b_l = t >> 5;

    // ---- t-table: t = (clip(x)+2)/h for this block's 16 samples x 256 dims ----
#pragma unroll
    for (int z = 0; z < 8; ++z) {
        int g = t + 512 * z;              // g = b_l*256 + i  (coalesced x read)
        float xv = x[b0 * DIN + g];
        float xc = fminf(fmaxf(xv, -2.0f), 2.0f);
        tT[g] = (xc + 2.0f) * INV_H;
    }

    const float4* yf4 = (const float4*)y;
    float4 pv0, pv1, pv2, pv3;            // register staging (async-STAGE split)

    // f in [0,2048): row = f>>4 (i_l*32 + o_s), kq = f&15 (16B quad within row)
    auto gidx = [&](int p, int f) {
        int row = f >> 4;
        int kq  = f & 15;
        int ig  = p * IS + (row >> 5);    // global input dim
        int os  = row & (OS - 1);
        return (((ig << 8) + o0 + os) << 4) + kq;   // float4 index into y
    };
    auto prefetch = [&](int p) {
        pv0 = yf4[gidx(p, t)];
        pv1 = yf4[gidx(p, t + 512)];
        pv2 = yf4[gidx(p, t + 1024)];
        pv3 = yf4[gidx(p, t + 1536)];
    };
    auto lwrite = [&](int f, float4 v) {
        int row = f >> 4;
        int kq  = f & 15;
        int e   = row * RSTR + 1 + 4 * kq;          // data lives at [1..64]
        buf[e + 0] = v.x; buf[e + 1] = v.y;
        buf[e + 2] = v.z; buf[e + 3] = v.w;
        if (kq == 0)  buf[row * RSTR]      = v.x;   // left ghost  = y[0]
        if (kq == 15) buf[row * RSTR + 65] = v.w;   // right ghost = y[63]
    };

    prefetch(0);
    __syncthreads();                       // tT ready

    float acc = 0.0f;
    for (int p = 0; p < NPH; ++p) {
        // write staged registers for phase p (compiler inserts vmcnt wait)
        lwrite(t,        pv0);
        lwrite(t + 512,  pv1);
        lwrite(t + 1024, pv2);
        lwrite(t + 1536, pv3);
        __syncthreads();                   // buf[p] visible

        if (p + 1 < NPH) prefetch(p + 1);  // issue loads; land during compute

#pragma unroll
        for (int il = 0; il < IS; ++il) {
            int ig = p * IS + il;
            float tv = tT[b_l * DIN + ig];           // broadcast LDS read
            int k = (int)tv;                         // tv >= 0 always
            k = k > NK - 1 ? NK - 1 : k;
            float u = tv - (float)k;

            int e = (il * OS + o_l) * RSTR + k;      // ghosted quad: y[k-1..k+2]
            float ym1 = buf[e + 0];
            float y0  = buf[e + 1];
            float y1  = buf[e + 2];
            float y2  = buf[e + 3];

            float dm1 = (y0 - ym1) * INV_H;          // 0 at k==0 (ghost dup)
            float d0  = (y1 - y0)  * INV_H;
            float d1  = (y2 - y1)  * INV_H;          // 0 at k==62 (ghost dup)

            float mk  = pchip_inner(dm1, d0);
            if (k == 0)      mk  = pchip_edge(d0, d1);    // rare, exec-masked
            float mk1 = pchip_inner(d0, d1);
            if (k == NK - 1) mk1 = pchip_edge(d0, dm1);   // rare, exec-masked

            float hm0 = HSTEP * mk;
            float hm1 = HSTEP * mk1;
            float dy  = y1 - y0;
            float a2  = 3.0f * dy - 2.0f * hm0 - hm1;     // u^2 coeff
            float a3  = hm0 + hm1 - 2.0f * dy;            // u^3 coeff
            acc += fmaf(u, fmaf(u, fmaf(u, a3, a2), hm0), y0);
        }
        __syncthreads();                   // all reads done before next write
    }

    out[(b0 + b_l) * DOUT + o0 + o_l] = acc + bias[o0 + o_l];
}

extern "C" void kernel_launch(void* const* d_in, const int* in_sizes, int n_in,
                              void* d_out, int out_size, void* d_ws, size_t ws_size,
                              hipStream_t stream) {
    const float* x    = (const float*)d_in[0];   // (B, DIN)
    const float* y    = (const float*)d_in[1];   // (DIN, DOUT, KNOTS)
    const float* bias = (const float*)d_in[2];   // (DOUT,)
    float* out        = (float*)d_out;           // (B, DOUT)

    (void)d_ws; (void)ws_size;                   // workspace intentionally unused

    kan_fused<<<dim3((B_SZ / BT) * (DOUT / OS)), dim3(512), 0, stream>>>(x, y, bias, out);
}

// Round 6
// 100.468 us; speedup vs baseline: 1.5841x; 1.5841x over previous
//
#include <hip/hip_runtime.h>
#include <cstdint>
#include <cstddef>

// Problem constants (from reference)
#define B_SZ   512
#define DIN    256
#define DOUT   256
#define KNOTS  64
#define NK     63                 // intervals = KNOTS-1
#define HSTEP  (4.0f / 63.0f)
#define INV_H  15.75f             // exact in f32

// XCD-affine slicing of the input dimension
#define NSLICE 8                  // = number of XCDs
#define ISLICE (DIN / NSLICE)     // 32 input dims -> 3.94 MiB table slice (fits 4 MiB L2)
#define SPB    4                  // samples per forward block

typedef _Float16 h2f __attribute__((ext_vector_type(2)));

// Per-interval table entry: {y0, y1-y0, h*m0, h*m1} as 4 x f16 = 8 B.
struct __align__(8) Ent { h2f ydy; h2f hmm; };

// Per-(b,i) record: table byte offset + hermite weights {1,h01} {h10,h11}.
struct __align__(16) Rec { int off; h2f w01; h2f w23; int pad; };

static_assert(sizeof(Ent) == 8,  "Ent must be 8 bytes");
static_assert(sizeof(Rec) == 16, "Rec must be 16 bytes");

#if defined(__has_builtin)
#  if __has_builtin(__builtin_amdgcn_fdot2)
#    define HAVE_FDOT2 1
#  endif
#endif

static __device__ __forceinline__ float dot2acc(h2f a, h2f b, float acc) {
#ifdef HAVE_FDOT2
    return __builtin_amdgcn_fdot2(a, b, acc, false);
#else
    return acc + (float)a.x * (float)b.x + (float)a.y * (float)b.y;
#endif
}

// ---- PCHIP slope helpers (reference semantics, f32 exact) ----
static __device__ __forceinline__ float pchip_edge(float dA, float dB) {
    float m = 0.5f * (3.0f * dA - dB);
    if (m * dA <= 0.0f) {
        m = 0.0f;
    } else if (dA * dB < 0.0f && fabsf(m) > 3.0f * fabsf(dA)) {
        m = 3.0f * dA;
    }
    return m;
}

static __device__ __forceinline__ float pchip_inner(float d0, float d1) {
    if (d0 * d1 > 0.0f) {
        float denom = d0 + d1;
        if (fabsf(denom) < 1e-12f) return 0.0f;
        return 2.0f * d0 * d1 / denom;
    }
    return 0.0f;
}

// ---- Kernel 1: build per-interval table + init out = bias ----
// XCD-affine: block beta handles input dim i = (beta%8)*32 + beta/8, so the
// written table lines are born dirty in the same XCD's L2 that kan_forward
// (slice = beta%8) will read them from.
__global__ __launch_bounds__(256) void build_coef(const float* __restrict__ y,
                                                  Ent* __restrict__ C,
                                                  const float* __restrict__ bias,
                                                  float* __restrict__ out) {
    const int beta = blockIdx.x;
    const int i = (beta & 7) * ISLICE + (beta >> 3);
    const int o = threadIdx.x;
    const float h = HSTEP;

    // out = bias init: 131072 floats over 65536 threads -> one float2 each.
    {
        int t2 = beta * 256 + o;
        int o0 = (o * 2) & (DOUT - 1);
        float2 bv;
        bv.x = bias[o0];
        bv.y = bias[o0 + 1];
        ((float2*)out)[t2] = bv;
    }

    const float4* r4 = (const float4*)(y + ((size_t)i * DOUT + o) * KNOTS);
    float yv[KNOTS];
#pragma unroll
    for (int q = 0; q < KNOTS / 4; ++q) {
        float4 v = r4[q];
        yv[4 * q + 0] = v.x; yv[4 * q + 1] = v.y;
        yv[4 * q + 2] = v.z; yv[4 * q + 3] = v.w;
    }
    float d[NK];
#pragma unroll
    for (int k = 0; k < NK; ++k) d[k] = (yv[k + 1] - yv[k]) / h;

    Ent* outp = C + (size_t)i * NK * DOUT + o;

    float mk = pchip_edge(d[0], d[1]);
#pragma unroll
    for (int k = 0; k < NK; ++k) {
        float mk1 = (k < NK - 1) ? pchip_inner(d[k], d[k + 1])
                                 : pchip_edge(d[NK - 1], d[NK - 2]);
        Ent e;
        e.ydy.x = (_Float16)yv[k];
        e.ydy.y = (_Float16)(yv[k + 1] - yv[k]);
        e.hmm.x = (_Float16)(h * mk);
        e.hmm.y = (_Float16)(h * mk1);
        outp[(size_t)k * DOUT] = e;
        mk = mk1;
    }
}

// ---- Kernel 2: forward pass — 5 instructions per term ----
// grid = (B/SPB) * NSLICE = 1024 blocks of 1024 threads (4 samples x 256 o).
// slice = bid%8 pins each block's 3.94 MiB table slice to one XCD's L2.
// Inner loop per term: broadcast ds_read_b128 (record), v_add_u32,
// global_load_dwordx2 (L2-hit), 2x v_dot2_f32_f16 into an f32 accumulator.
__global__ __launch_bounds__(1024) void kan_forward(const float* __restrict__ x,
                                                    const Ent* __restrict__ C,
                                                    float* __restrict__ out) {
    __shared__ Rec recs[SPB * ISLICE];    // 128 records x 16 B = 2 KB

    const int bid   = blockIdx.x;
    const int slice = bid & (NSLICE - 1);
    const int chunk = bid >> 3;
    const int tid   = threadIdx.x;

    if (tid < SPB * ISLICE) {             // 128 threads stage the records
        const int s = tid >> 5;
        const int j = tid & (ISLICE - 1);
        const int b = chunk * SPB + s;
        const int i = slice * ISLICE + j;
        float xv = x[b * DIN + i];
        float xc = fminf(fmaxf(xv, -2.0f), 2.0f);
        float tv = (xc + 2.0f) * INV_H;
        int k = (int)tv;                  // tv >= 0
        k = k > NK - 1 ? NK - 1 : k;
        float u   = tv - (float)k;
        float u2  = u * u;
        float um1 = u - 1.0f;
        float c1  = u2 * (3.0f - 2.0f * u);   // h01
        float c2  = u * um1 * um1;            // h10
        float c3  = u2 * um1;                 // h11
        Rec r;
        r.off   = (i * NK + k) << 11;         // *DOUT*sizeof(Ent) = *2048 bytes
        r.w01.x = (_Float16)1.0f;
        r.w01.y = (_Float16)c1;
        r.w23.x = (_Float16)c2;
        r.w23.y = (_Float16)c3;
        r.pad   = 0;
        recs[tid] = r;
    }
    __syncthreads();

    const int s  = tid >> 8;              // sample 0..3
    const int o  = tid & (DOUT - 1);
    const unsigned ob = (unsigned)o * (unsigned)sizeof(Ent);  // loop-invariant
    const char* base = (const char*)C;

    float acc = 0.0f;
#pragma unroll 8
    for (int j = 0; j < ISLICE; ++j) {
        Rec r = recs[s * ISLICE + j];                       // broadcast b128
        const Ent* e = (const Ent*)(base + ((unsigned)r.off + ob));
        Ent v = *e;                                         // 8 B, L2-resident
        acc = dot2acc(v.ydy, r.w01, acc);                   // y0*1 + dy*h01
        acc = dot2acc(v.hmm, r.w23, acc);                   // hm0*h10 + hm1*h11
    }
    atomicAdd(&out[(chunk * SPB + s) * DOUT + o], acc);
}

// ---- Fallback: no-workspace path (only if ws_size is too small) ----
__global__ __launch_bounds__(256) void kan_naive(const float* __restrict__ x,
                                                 const float* __restrict__ y,
                                                 const float* __restrict__ bias,
                                                 float* __restrict__ out) {
    __shared__ int   sk[DIN];
    __shared__ float su[DIN];

    const int b   = blockIdx.x;
    const int tid = threadIdx.x;
    const float h = HSTEP;

    {
        float xv = x[b * DIN + tid];
        float xc = fminf(fmaxf(xv, -2.0f), 2.0f);
        float t  = (xc + 2.0f) / h;
        int k = (int)floorf(t);
        k = k < 0 ? 0 : (k > NK - 1 ? NK - 1 : k);
        sk[tid] = k;
        su[tid] = t - (float)k;
    }
    __syncthreads();

    const int o = tid;
    float acc = 0.0f;
    for (int i = 0; i < DIN; ++i) {
        int   k = sk[i];
        float u = su[i];
        const float* r = y + ((size_t)i * DOUT + o) * KNOTS;
        float ym1 = r[k > 0 ? k - 1 : 0];
        float y0  = r[k];
        float y1  = r[k + 1];
        float y2  = r[k < NK - 1 ? k + 2 : KNOTS - 1];
        float dm1 = (y0 - ym1) / h;
        float d0  = (y1 - y0) / h;
        float d1  = (y2 - y1) / h;
        float mk  = (k == 0)      ? pchip_edge(d0, d1)  : pchip_inner(dm1, d0);
        float mk1 = (k == NK - 1) ? pchip_edge(d0, dm1) : pchip_inner(d0, d1);
        float hm0 = h * mk, hm1 = h * mk1;
        float dy = y1 - y0;
        float c2 = 3.0f * dy - 2.0f * hm0 - hm1;
        float c3 = hm0 + hm1 - 2.0f * dy;
        acc += fmaf(u, fmaf(u, fmaf(u, c3, c2), hm0), y0);
    }
    out[b * DOUT + o] = acc + bias[o];
}

extern "C" void kernel_launch(void* const* d_in, const int* in_sizes, int n_in,
                              void* d_out, int out_size, void* d_ws, size_t ws_size,
                              hipStream_t stream) {
    const float* x    = (const float*)d_in[0];   // (B, DIN)
    const float* y    = (const float*)d_in[1];   // (DIN, DOUT, KNOTS)
    const float* bias = (const float*)d_in[2];   // (DOUT,)
    float* out        = (float*)d_out;           // (B, DOUT)

    const size_t need = (size_t)DIN * NK * DOUT * sizeof(Ent); // ~33 MB

    if (ws_size >= need) {
        Ent* C = (Ent*)d_ws;
        build_coef<<<dim3(DIN), dim3(256), 0, stream>>>(y, C, bias, out);
        kan_forward<<<dim3((B_SZ / SPB) * NSLICE), dim3(1024), 0, stream>>>(x, C, out);
    } else {
        kan_naive<<<dim3(B_SZ), dim3(256), 0, stream>>>(x, y, bias, out);
    }
}